// Round 2
// baseline (446.779 us; speedup 1.0000x reference)
//
#include <hip/hip_runtime.h>
#include <cstdint>

#define DIM 128
#define MTILE 64        // edges/nodes per block-tile
#define PAIR_LD 264     // ushorts per pair row (256 + 8 pad) -- fallback kernel
#define H_LD 136        // ushorts per h row  (128 + 8 pad)

typedef __bf16 v8bf __attribute__((ext_vector_type(8)));
typedef _Float16 v8hf __attribute__((ext_vector_type(8)));
typedef float v16f __attribute__((ext_vector_type(16)));

static __device__ __forceinline__ unsigned int f2bf_pack(float a, float b) {
  union { float f; unsigned u; } x, y; x.f = a; y.f = b;
  unsigned lo = (x.u + 0x7FFFu + ((x.u >> 16) & 1u)) >> 16;
  unsigned hi = (y.u + 0x7FFFu + ((y.u >> 16) & 1u)) >> 16;
  return lo | (hi << 16);
}
static __device__ __forceinline__ unsigned short f2bf(float a) {
  union { float f; unsigned u; } x; x.f = a;
  return (unsigned short)((x.u + 0x7FFFu + ((x.u >> 16) & 1u)) >> 16);
}
static __device__ __forceinline__ unsigned short f2h(float a) {
  union { _Float16 h; unsigned short u; } c; c.h = (_Float16)a; return c.u;
}
static __device__ __forceinline__ float bfhi2f(unsigned int hi16) {
  union { unsigned u; float f; } c; c.u = hi16; return c.f;
}

// prep: weight transpose/convert only. W1t bf16 (node_precompute / fallback
// GEMM1); W2t fp16 when y-cached path runs, bf16 for the fallback.
__global__ __launch_bounds__(256) void prep_w(
    const float* __restrict__ W1, const float* __restrict__ W2,
    unsigned short* __restrict__ W1t, unsigned short* __restrict__ W2t,
    int w2_f16) {
  int i = blockIdx.x * 256 + threadIdx.x;
  if (i < 32768) {
    int n = i >> 8, k = i & 255;
    W1t[i] = f2bf(W1[k * 128 + n]);
  } else if (i < 49152) {
    int j = i - 32768;
    int n = j >> 7, k = j & 127;
    float v = W2[k * 128 + n];
    W2t[j] = w2_f16 ? f2h(v) : f2bf(v);
  }
}

// Round-8 node_precompute v2: `which` split across the grid (2x blocks).
// Per block: only 8 B1 fragments (32 VGPR, was 64), one stage->MFMA->store
// pass (2 barriers, was 3 per half), 4 blocks/CU (was 2). y stored fp16;
// b1 folded into y2 only.
__global__ __launch_bounds__(256, 4) void node_precompute(
    const float* __restrict__ x1, const float* __restrict__ x2,
    const unsigned short* __restrict__ W1t, const float* __restrict__ b1,
    unsigned short* __restrict__ y1c, unsigned short* __restrict__ y2c,
    int nnodes)
{
  __shared__ unsigned short sm_x[MTILE * H_LD];
  __shared__ unsigned short sm_y[MTILE * H_LD];

  const int tid = threadIdx.x;
  const int lane = tid & 63;
  const int wv = tid >> 6;
  const int l31 = lane & 31;
  const int l5 = lane >> 5;
  const int nb = wv * 32 + l31;
  const int rslot = tid >> 4;
  const int lane16 = tid & 15;

  const int which = blockIdx.x & 1;          // 0: y1 = x1@W1_top, 1: y2 = x2@W1_bot + b1
  const int base = (blockIdx.x >> 1) * MTILE;
  const int nvalid = nnodes - base;          // < 64 only in the last tile
  const float* xs = which ? x2 : x1;
  unsigned short* yd = which ? y2c : y1c;

  v8bf B1[8];
#pragma unroll
  for (int kt = 0; kt < 8; ++kt)
    B1[kt] = *reinterpret_cast<const v8bf*>(W1t + nb * 256 + which * 128 + kt * 16 + l5 * 8);
  const float badd = which ? b1[nb] : 0.f;

  // stage x tile (fp32 -> bf16), coalesced 32B/thread
#pragma unroll
  for (int p = 0; p < 4; ++p) {
    int el = p * 16 + rslot;
    int row = base + el; if (row >= nnodes) row = nnodes - 1;
    const float4* s = reinterpret_cast<const float4*>(xs + (size_t)row * DIM) + lane16 * 2;
    float4 f0 = s[0];
    float4 f1 = s[1];
    uint4 pk;
    pk.x = f2bf_pack(f0.x, f0.y);
    pk.y = f2bf_pack(f0.z, f0.w);
    pk.z = f2bf_pack(f1.x, f1.y);
    pk.w = f2bf_pack(f1.z, f1.w);
    *reinterpret_cast<uint4*>(&sm_x[el * H_LD + lane16 * 8]) = pk;
  }
  __syncthreads();

  // y-half = x @ W1_half, fp16 out into sm_y
#pragma unroll
  for (int h = 0; h < 2; ++h) {
    v16f acc;
#pragma unroll
    for (int r = 0; r < 16; ++r) acc[r] = 0.f;
#pragma unroll
    for (int kt = 0; kt < 8; ++kt) {
      v8bf a = *reinterpret_cast<const v8bf*>(&sm_x[(32 * h + l31) * H_LD + kt * 16 + l5 * 8]);
      acc = __builtin_amdgcn_mfma_f32_32x32x16_bf16(a, B1[kt], acc, 0, 0, 0);
    }
#pragma unroll
    for (int r = 0; r < 16; ++r) {
      int m = 32 * h + (r & 3) + 8 * (r >> 2) + 4 * l5;  // C/D row map (m74/m101)
      sm_y[m * H_LD + nb] = f2h(acc[r] + badd);
    }
  }
  __syncthreads();

  // coalesced fp16 write-out
#pragma unroll
  for (int p = 0; p < 4; ++p) {
    int el = p * 16 + rslot;
    if (el < nvalid)
      *reinterpret_cast<uint4*>(yd + (size_t)(base + el) * DIM + lane16 * 8) =
          *reinterpret_cast<const uint4*>(&sm_y[el * H_LD + lane16 * 8]);
  }
}

// Round-8 edge kernel: same structure as round-7 (gather y-rows,
// h1 = relu(y1+y2) packed fp16, GEMM2 f16 MFMA transposed, GEMM3
// in-register) but register diet for 6 blocks/CU (was 4):
//   w3r/b2r (32 persistent VGPRs) -> LDS; reads are half-wave-uniform
//   (same addr across l31) so they broadcast conflict-free.
// Persistent regs: B2(32) + idxr(8) + misc ~= 50; peak with 8 in-flight
// gather uint4s ~= 82 <= 85-reg cap at waves/EU=6.
__global__ __launch_bounds__(256, 6) void mlp_edge_y(
    const int* __restrict__ eidx,
    const unsigned short* __restrict__ W2t,   // fp16 [n=128][k=128]
    const float* __restrict__ b2, const float* __restrict__ W3,
    const float* __restrict__ b3, float* __restrict__ out,
    int E, int ntiles,
    const unsigned short* __restrict__ y1c, const unsigned short* __restrict__ y2c)
{
  __shared__ unsigned short sm_h1[MTILE * H_LD];   // 17408 B
  __shared__ float sm_part[4 * MTILE];             // 1024 B
  __shared__ float sm_w3[DIM];                     // 512 B
  __shared__ float sm_b2[DIM];                     // 512 B

  const int tid = threadIdx.x;
  const int lane = tid & 63;
  const int wv = tid >> 6;        // wave -> n-slice [32*wv, 32*wv+32)
  const int l31 = lane & 31;
  const int l5 = lane >> 5;
  const int nb = wv * 32 + l31;

  if (tid < 128) { sm_w3[tid] = W3[tid]; sm_b2[tid] = b2[tid]; }

  v8hf B2[8];
#pragma unroll
  for (int kt = 0; kt < 8; ++kt)
    B2[kt] = *reinterpret_cast<const v8hf*>(W2t + nb * 128 + kt * 16 + l5 * 8);
  const float bias3 = b3[0];
  const int n2b = wv * 32 + 4 * l5;   // n2(r) = n2b + (r&3) + 8*(r>>2)

  const int rslot = tid >> 4;     // 0..15: edge-row slot within a pass
  const int lane16 = tid & 15;    // 16 lanes x 8 fp16 cover one 128-wide row

  // preamble: indices for the first tile (idxr[0..3]=src, [4..7]=dst)
  int idxr[8];
  {
    const int t0 = min((int)blockIdx.x, ntiles - 1);
    const size_t e0 = (size_t)t0 * MTILE;
#pragma unroll
    for (int p = 0; p < 8; ++p) {
      int el = (p & 3) * 16 + rslot;
      idxr[p] = eidx[e0 + el + ((p >= 4) ? (size_t)E : 0)];
    }
  }

  int eprev = -1;

  for (int tile = blockIdx.x; tile < ntiles; tile += gridDim.x) {
    __syncthreads();  // A: sm_h1 free (GEMM2 readers done), partials ready

    // gather both endpoints of each edge-row slice (issue all loads first)
    uint4 av[4], bv[4];
#pragma unroll
    for (int p = 0; p < 4; ++p) {
      av[p] = *reinterpret_cast<const uint4*>(y1c + (size_t)idxr[p] * DIM + lane16 * 8);
      bv[p] = *reinterpret_cast<const uint4*>(y2c + (size_t)idxr[p + 4] * DIM + lane16 * 8);
    }

    // deferred final reduce of PREVIOUS tile (overlaps gather latency)
    if (eprev >= 0 && tid < MTILE) {
      float s = sm_part[tid] + sm_part[64 + tid] + sm_part[128 + tid] + sm_part[192 + tid];
      out[eprev + tid] = s + bias3;
    }

    // h1 = relu(y1 + y2) in packed fp16, straight to LDS (short live range)
#pragma unroll
    for (int p = 0; p < 4; ++p) {
      union { uint4 u; v8hf h; } a, b;
      a.u = av[p]; b.u = bv[p];
      v8hf s = a.h + b.h;
#pragma unroll
      for (int j = 0; j < 8; ++j) s[j] = s[j] > (_Float16)0 ? s[j] : (_Float16)0;
      union { v8hf h; uint4 u; } r; r.h = s;
      int el = p * 16 + rslot;
      *reinterpret_cast<uint4*>(&sm_h1[el * H_LD + lane16 * 8]) = r.u;
    }

    // prefetch next tile's indices (8 scalar ints, land during GEMM2)
    {
      const int tn = min(tile + (int)gridDim.x, ntiles - 1);
      const size_t en = (size_t)tn * MTILE;
#pragma unroll
      for (int p = 0; p < 8; ++p) {
        int el = (p & 3) * 16 + rslot;
        idxr[p] = eidx[en + el + ((p >= 4) ? (size_t)E : 0)];
      }
    }
    __syncthreads();  // B: h1 ready

    // GEMM2 (transposed: h2^T = W2t @ h1^T) + GEMM3 in-register
#pragma unroll
    for (int h = 0; h < 2; ++h) {
      v16f acc;
#pragma unroll
      for (int r = 0; r < 16; ++r) acc[r] = 0.f;
#pragma unroll
      for (int kt = 0; kt < 8; ++kt) {
        v8hf bf = *reinterpret_cast<const v8hf*>(&sm_h1[(32 * h + l31) * H_LD + kt * 16 + l5 * 8]);
        acc = __builtin_amdgcn_mfma_f32_32x32x16_f16(B2[kt], bf, acc, 0, 0, 0);
      }
      float p = 0.f;
#pragma unroll
      for (int r = 0; r < 16; ++r) {
        int n2 = n2b + (r & 3) + 8 * (r >> 2);
        p += fmaxf(acc[r] + sm_b2[n2], 0.f) * sm_w3[n2];  // half-wave-uniform LDS reads
      }
      p += __shfl_xor(p, 32);          // combine l5 halves
      if (l5 == 0) sm_part[wv * 64 + 32 * h + l31] = p;
    }

    eprev = tile * MTILE;
  }

  __syncthreads();
  if (eprev >= 0 && tid < MTILE) {
    float s = sm_part[tid] + sm_part[64 + tid] + sm_part[128 + tid] + sm_part[192 + tid];
    out[eprev + tid] = s + bias3;
  }
}

// Fallback (ws too small for y cache): unchanged round-6 structure.
__global__ __launch_bounds__(256, 2) void mlp_edge_direct(
    const float* __restrict__ x1, const float* __restrict__ x2,
    const int* __restrict__ eidx,
    const unsigned short* __restrict__ W1t, const unsigned short* __restrict__ W2t,
    const float* __restrict__ b1, const float* __restrict__ b2,
    const float* __restrict__ W3, const float* __restrict__ b3,
    float* __restrict__ out, int E, int ntiles)
{
  __shared__ unsigned short sm_pair[MTILE * PAIR_LD];
  __shared__ unsigned short sm_h1[MTILE * H_LD];
  __shared__ float sm_w3[4 * 36];
  unsigned short* sm_h2 = sm_pair;

  const int tid = threadIdx.x;
  const int lane = tid & 63;
  const int wv = tid >> 6;
  const int l31 = lane & 31;
  const int l5 = lane >> 5;
  const int nb = wv * 32 + l31;

  v8bf B1[16], B2[8];
#pragma unroll
  for (int kt = 0; kt < 16; ++kt)
    B1[kt] = *reinterpret_cast<const v8bf*>(W1t + nb * 256 + kt * 16 + l5 * 8);
#pragma unroll
  for (int kt = 0; kt < 8; ++kt)
    B2[kt] = *reinterpret_cast<const v8bf*>(W2t + nb * 128 + kt * 16 + l5 * 8);
  const float b1v = b1[nb];
  const float b2v = b2[nb];
  const float bias3 = b3[0];
  if (tid < 128) sm_w3[(tid >> 5) * 36 + (tid & 31)] = W3[tid];

  const int rslot = tid >> 4;
  const int lane16 = tid & 15;
  const int part = tid & 3;

  for (int tile = blockIdx.x; tile < ntiles; tile += gridDim.x) {
    __syncthreads();
    const int e0 = tile * MTILE;
#pragma unroll
    for (int p = 0; p < 8; ++p) {
      int rowid = p * 16 + rslot;
      int half = rowid >> 6;
      int el = rowid & 63;
      int node = eidx[e0 + el + (half ? E : 0)];
      const float* src = (half ? x2 : x1) + (size_t)node * DIM + lane16 * 8;
      float4 f0 = *reinterpret_cast<const float4*>(src);
      float4 f1 = *reinterpret_cast<const float4*>(src + 4);
      uint4 pk;
      pk.x = f2bf_pack(f0.x, f0.y);
      pk.y = f2bf_pack(f0.z, f0.w);
      pk.z = f2bf_pack(f1.x, f1.y);
      pk.w = f2bf_pack(f1.z, f1.w);
      *reinterpret_cast<uint4*>(&sm_pair[el * PAIR_LD + half * 128 + lane16 * 8]) = pk;
    }
    __syncthreads();

    v16f acc0, acc1;
#pragma unroll
    for (int r = 0; r < 16; ++r) { acc0[r] = 0.f; acc1[r] = 0.f; }
#pragma unroll
    for (int kt = 0; kt < 16; ++kt) {
      v8bf a0 = *reinterpret_cast<const v8bf*>(&sm_pair[l31 * PAIR_LD + kt * 16 + l5 * 8]);
      v8bf a1 = *reinterpret_cast<const v8bf*>(&sm_pair[(32 + l31) * PAIR_LD + kt * 16 + l5 * 8]);
      acc0 = __builtin_amdgcn_mfma_f32_32x32x16_bf16(a0, B1[kt], acc0, 0, 0, 0);
      acc1 = __builtin_amdgcn_mfma_f32_32x32x16_bf16(a1, B1[kt], acc1, 0, 0, 0);
    }
#pragma unroll
    for (int r = 0; r < 16; ++r) {
      int m = (r & 3) + 8 * (r >> 2) + 4 * l5;
      sm_h1[m * H_LD + nb] = f2bf(fmaxf(acc0[r] + b1v, 0.f));
      sm_h1[(32 + m) * H_LD + nb] = f2bf(fmaxf(acc1[r] + b1v, 0.f));
    }
    __syncthreads();

    v16f c0, c1;
#pragma unroll
    for (int r = 0; r < 16; ++r) { c0[r] = 0.f; c1[r] = 0.f; }
#pragma unroll
    for (int kt = 0; kt < 8; ++kt) {
      v8bf a0 = *reinterpret_cast<const v8bf*>(&sm_h1[l31 * H_LD + kt * 16 + l5 * 8]);
      v8bf a1 = *reinterpret_cast<const v8bf*>(&sm_h1[(32 + l31) * H_LD + kt * 16 + l5 * 8]);
      c0 = __builtin_amdgcn_mfma_f32_32x32x16_bf16(a0, B2[kt], c0, 0, 0, 0);
      c1 = __builtin_amdgcn_mfma_f32_32x32x16_bf16(a1, B2[kt], c1, 0, 0, 0);
    }
#pragma unroll
    for (int r = 0; r < 16; ++r) {
      int m = (r & 3) + 8 * (r >> 2) + 4 * l5;
      sm_h2[m * H_LD + nb] = f2bf(fmaxf(c0[r] + b2v, 0.f));
      sm_h2[(32 + m) * H_LD + nb] = f2bf(fmaxf(c1[r] + b2v, 0.f));
    }
    __syncthreads();

    {
      int el = tid >> 2;
      const unsigned short* hrow = &sm_h2[el * H_LD + part * 32];
      const float* wrow = &sm_w3[part * 36];
      float sum = 0.f;
#pragma unroll
      for (int j = 0; j < 4; ++j) {
        uint4 u = *reinterpret_cast<const uint4*>(hrow + j * 8);
        float4 wa = *reinterpret_cast<const float4*>(wrow + j * 8);
        float4 wb = *reinterpret_cast<const float4*>(wrow + j * 8 + 4);
        sum += bfhi2f(u.x << 16) * wa.x + bfhi2f(u.x & 0xFFFF0000u) * wa.y;
        sum += bfhi2f(u.y << 16) * wa.z + bfhi2f(u.y & 0xFFFF0000u) * wa.w;
        sum += bfhi2f(u.z << 16) * wb.x + bfhi2f(u.z & 0xFFFF0000u) * wb.y;
        sum += bfhi2f(u.w << 16) * wb.z + bfhi2f(u.w & 0xFFFF0000u) * wb.w;
      }
      sum += __shfl_xor(sum, 1, 64);
      sum += __shfl_xor(sum, 2, 64);
      if (part == 0) out[e0 + el] = sum + bias3;
    }
  }
}

extern "C" void kernel_launch(void* const* d_in, const int* in_sizes, int n_in,
                              void* d_out, int out_size, void* d_ws, size_t ws_size,
                              hipStream_t stream) {
  const float* x1 = (const float*)d_in[0];
  const float* x2 = (const float*)d_in[1];
  const int* eidx = (const int*)d_in[2];
  const float* W1 = (const float*)d_in[3];
  const float* b1 = (const float*)d_in[4];
  const float* W2 = (const float*)d_in[5];
  const float* b2 = (const float*)d_in[6];
  const float* W3 = (const float*)d_in[7];
  const float* b3 = (const float*)d_in[8];
  float* out = (float*)d_out;

  int E = in_sizes[2] / 2;
  if (E <= 0) return;
  int ntiles = E / MTILE;           // E = 1,600,000 divisible by 64
  int nelem = in_sizes[0];          // nodes * DIM
  int nnodes = nelem / DIM;

  unsigned short* W1t = (unsigned short*)d_ws;         // 32768 bf16
  unsigned short* W2t = W1t + 32768;                   // 16384 bf16/fp16
  size_t woff = 98304;                                 // bytes used by weights
  size_t need = woff + 2 * (size_t)nelem * 2;          // y1c + y2c fp16
  int use_cache = (ws_size >= need) ? 1 : 0;
  unsigned short* y1c = (unsigned short*)((char*)d_ws + woff);
  unsigned short* y2c = y1c + nelem;

  prep_w<<<192, 256, 0, stream>>>(W1, W2, W1t, W2t, use_cache);

  if (use_cache) {
    int ntn = (nnodes + MTILE - 1) / MTILE;
    node_precompute<<<2 * ntn, 256, 0, stream>>>(x1, x2, W1t, b1, y1c, y2c, nnodes);
    mlp_edge_y<<<1536, 256, 0, stream>>>(eidx, W2t, b2, W3, b3,
                                         out, E, ntiles, y1c, y2c);
  } else {
    mlp_edge_direct<<<512, 256, 0, stream>>>(x1, x2, eidx, W1t, W2t,
                                             b1, b2, W3, b3, out, E, ntiles);
  }
}

// Round 3
// 256.342 us; speedup vs baseline: 1.7429x; 1.7429x over previous
//
#include <hip/hip_runtime.h>
#include <cstdint>

#define DIM 128
#define MTILE 64        // edges/nodes per block-tile
#define PAIR_LD 264     // ushorts per pair row (256 + 8 pad) -- fallback kernel
#define H_LD 136        // ushorts per h row  (128 + 8 pad)

typedef __bf16 v8bf __attribute__((ext_vector_type(8)));
typedef _Float16 v8hf __attribute__((ext_vector_type(8)));
typedef float v16f __attribute__((ext_vector_type(16)));

static __device__ __forceinline__ unsigned int f2bf_pack(float a, float b) {
  union { float f; unsigned u; } x, y; x.f = a; y.f = b;
  unsigned lo = (x.u + 0x7FFFu + ((x.u >> 16) & 1u)) >> 16;
  unsigned hi = (y.u + 0x7FFFu + ((y.u >> 16) & 1u)) >> 16;
  return lo | (hi << 16);
}
static __device__ __forceinline__ unsigned short f2bf(float a) {
  union { float f; unsigned u; } x; x.f = a;
  return (unsigned short)((x.u + 0x7FFFu + ((x.u >> 16) & 1u)) >> 16);
}
static __device__ __forceinline__ unsigned short f2h(float a) {
  union { _Float16 h; unsigned short u; } c; c.h = (_Float16)a; return c.u;
}
static __device__ __forceinline__ float bfhi2f(unsigned int hi16) {
  union { unsigned u; float f; } c; c.u = hi16; return c.f;
}

// prep: weight transpose/convert only. W1t bf16 (node_precompute / fallback
// GEMM1); W2t fp16 when y-cached path runs, bf16 for the fallback.
__global__ __launch_bounds__(256) void prep_w(
    const float* __restrict__ W1, const float* __restrict__ W2,
    unsigned short* __restrict__ W1t, unsigned short* __restrict__ W2t,
    int w2_f16) {
  int i = blockIdx.x * 256 + threadIdx.x;
  if (i < 32768) {
    int n = i >> 8, k = i & 255;
    W1t[i] = f2bf(W1[k * 128 + n]);
  } else if (i < 49152) {
    int j = i - 32768;
    int n = j >> 7, k = j & 127;
    float v = W2[k * 128 + n];
    W2t[j] = w2_f16 ? f2h(v) : f2bf(v);
  }
}

// node_precompute v2 (round-2, kept): `which` split across the grid.
// Per block: 8 B1 fragments (32 VGPR), one stage->MFMA->store pass,
// 4 blocks/CU. y stored fp16; b1 folded into y2 only.
__global__ __launch_bounds__(256, 4) void node_precompute(
    const float* __restrict__ x1, const float* __restrict__ x2,
    const unsigned short* __restrict__ W1t, const float* __restrict__ b1,
    unsigned short* __restrict__ y1c, unsigned short* __restrict__ y2c,
    int nnodes)
{
  __shared__ unsigned short sm_x[MTILE * H_LD];
  __shared__ unsigned short sm_y[MTILE * H_LD];

  const int tid = threadIdx.x;
  const int lane = tid & 63;
  const int wv = tid >> 6;
  const int l31 = lane & 31;
  const int l5 = lane >> 5;
  const int nb = wv * 32 + l31;
  const int rslot = tid >> 4;
  const int lane16 = tid & 15;

  const int which = blockIdx.x & 1;          // 0: y1 = x1@W1_top, 1: y2 = x2@W1_bot + b1
  const int base = (blockIdx.x >> 1) * MTILE;
  const int nvalid = nnodes - base;          // < 64 only in the last tile
  const float* xs = which ? x2 : x1;
  unsigned short* yd = which ? y2c : y1c;

  v8bf B1[8];
#pragma unroll
  for (int kt = 0; kt < 8; ++kt)
    B1[kt] = *reinterpret_cast<const v8bf*>(W1t + nb * 256 + which * 128 + kt * 16 + l5 * 8);
  const float badd = which ? b1[nb] : 0.f;

  // stage x tile (fp32 -> bf16), coalesced 32B/thread
#pragma unroll
  for (int p = 0; p < 4; ++p) {
    int el = p * 16 + rslot;
    int row = base + el; if (row >= nnodes) row = nnodes - 1;
    const float4* s = reinterpret_cast<const float4*>(xs + (size_t)row * DIM) + lane16 * 2;
    float4 f0 = s[0];
    float4 f1 = s[1];
    uint4 pk;
    pk.x = f2bf_pack(f0.x, f0.y);
    pk.y = f2bf_pack(f0.z, f0.w);
    pk.z = f2bf_pack(f1.x, f1.y);
    pk.w = f2bf_pack(f1.z, f1.w);
    *reinterpret_cast<uint4*>(&sm_x[el * H_LD + lane16 * 8]) = pk;
  }
  __syncthreads();

  // y-half = x @ W1_half, fp16 out into sm_y
#pragma unroll
  for (int h = 0; h < 2; ++h) {
    v16f acc;
#pragma unroll
    for (int r = 0; r < 16; ++r) acc[r] = 0.f;
#pragma unroll
    for (int kt = 0; kt < 8; ++kt) {
      v8bf a = *reinterpret_cast<const v8bf*>(&sm_x[(32 * h + l31) * H_LD + kt * 16 + l5 * 8]);
      acc = __builtin_amdgcn_mfma_f32_32x32x16_bf16(a, B1[kt], acc, 0, 0, 0);
    }
#pragma unroll
    for (int r = 0; r < 16; ++r) {
      int m = 32 * h + (r & 3) + 8 * (r >> 2) + 4 * l5;  // C/D row map (m74/m101)
      sm_y[m * H_LD + nb] = f2h(acc[r] + badd);
    }
  }
  __syncthreads();

  // coalesced fp16 write-out
#pragma unroll
  for (int p = 0; p < 4; ++p) {
    int el = p * 16 + rslot;
    if (el < nvalid)
      *reinterpret_cast<uint4*>(yd + (size_t)(base + el) * DIM + lane16 * 8) =
          *reinterpret_cast<const uint4*>(&sm_y[el * H_LD + lane16 * 8]);
  }
}

// Round-9 edge kernel: EXACT round-1 body (proven: VGPR=60, no spill,
// 116 us @ grid 1024). Round-2's (256,6) register diet spilled
// (WRITE_SIZE 6.25->67 MB) -- reverted. The occupancy lever is the GRID:
// at 60 VGPR + 18.4 KB LDS the HW fits 8 blocks/CU (512/60=8 waves/EU,
// 8x18.4KB=147KB<160KB), so launch 2048 blocks instead of 1024.
// __launch_bounds__(256,4) only caps the allocator at 128 regs; actual
// residency is usage-driven -> 8 blocks/CU.
__global__ __launch_bounds__(256, 4) void mlp_edge_y(
    const int* __restrict__ eidx,
    const unsigned short* __restrict__ W2t,   // fp16 [n=128][k=128]
    const float* __restrict__ b2, const float* __restrict__ W3,
    const float* __restrict__ b3, float* __restrict__ out,
    int E, int ntiles,
    const unsigned short* __restrict__ y1c, const unsigned short* __restrict__ y2c)
{
  __shared__ unsigned short sm_h1[MTILE * H_LD];   // 17408 B
  __shared__ float sm_part[4 * MTILE];             // 1024 B

  const int tid = threadIdx.x;
  const int lane = tid & 63;
  const int wv = tid >> 6;        // wave -> n-slice [32*wv, 32*wv+32)
  const int l31 = lane & 31;
  const int l5 = lane >> 5;
  const int nb = wv * 32 + l31;

  v8hf B2[8];
#pragma unroll
  for (int kt = 0; kt < 8; ++kt)
    B2[kt] = *reinterpret_cast<const v8hf*>(W2t + nb * 128 + kt * 16 + l5 * 8);
  const float bias3 = b3[0];

  float w3r[16], b2r[16];
#pragma unroll
  for (int r = 0; r < 16; ++r) {
    int n2 = wv * 32 + (r & 3) + 8 * (r >> 2) + 4 * l5;
    w3r[r] = W3[n2];
    b2r[r] = b2[n2];
  }

  const int rslot = tid >> 4;     // 0..15: edge-row slot within a pass
  const int lane16 = tid & 15;    // 16 lanes x 8 fp16 cover one 128-wide row

  // preamble: indices for the first tile (idxr[0..3]=src, [4..7]=dst)
  int idxr[8];
  {
    const int t0 = min((int)blockIdx.x, ntiles - 1);
    const size_t e0 = (size_t)t0 * MTILE;
#pragma unroll
    for (int p = 0; p < 8; ++p) {
      int el = (p & 3) * 16 + rslot;
      idxr[p] = eidx[e0 + el + ((p >= 4) ? (size_t)E : 0)];
    }
  }

  int eprev = -1;

  for (int tile = blockIdx.x; tile < ntiles; tile += gridDim.x) {
    __syncthreads();  // A: sm_h1 free (GEMM2 readers done), partials ready

    // gather both endpoints of each edge-row slice (issue all loads first)
    uint4 av[4], bv[4];
#pragma unroll
    for (int p = 0; p < 4; ++p) {
      av[p] = *reinterpret_cast<const uint4*>(y1c + (size_t)idxr[p] * DIM + lane16 * 8);
      bv[p] = *reinterpret_cast<const uint4*>(y2c + (size_t)idxr[p + 4] * DIM + lane16 * 8);
    }

    // deferred final reduce of PREVIOUS tile (overlaps gather latency)
    if (eprev >= 0 && tid < MTILE) {
      float s = sm_part[tid] + sm_part[64 + tid] + sm_part[128 + tid] + sm_part[192 + tid];
      out[eprev + tid] = s + bias3;
    }

    // h1 = relu(y1 + y2) in packed fp16, straight to LDS (short live range)
#pragma unroll
    for (int p = 0; p < 4; ++p) {
      union { uint4 u; v8hf h; } a, b;
      a.u = av[p]; b.u = bv[p];
      v8hf s = a.h + b.h;
#pragma unroll
      for (int j = 0; j < 8; ++j) s[j] = s[j] > (_Float16)0 ? s[j] : (_Float16)0;
      union { v8hf h; uint4 u; } r; r.h = s;
      int el = p * 16 + rslot;
      *reinterpret_cast<uint4*>(&sm_h1[el * H_LD + lane16 * 8]) = r.u;
    }

    // prefetch next tile's indices (8 scalar ints, land during GEMM2)
    {
      const int tn = min(tile + (int)gridDim.x, ntiles - 1);
      const size_t en = (size_t)tn * MTILE;
#pragma unroll
      for (int p = 0; p < 8; ++p) {
        int el = (p & 3) * 16 + rslot;
        idxr[p] = eidx[en + el + ((p >= 4) ? (size_t)E : 0)];
      }
    }
    __syncthreads();  // B: h1 ready

    // GEMM2 (transposed: h2^T = W2t @ h1^T) + GEMM3 in-register
#pragma unroll
    for (int h = 0; h < 2; ++h) {
      v16f acc;
#pragma unroll
      for (int r = 0; r < 16; ++r) acc[r] = b2r[r];  // bias-init
#pragma unroll
      for (int kt = 0; kt < 8; ++kt) {
        v8hf bf = *reinterpret_cast<const v8hf*>(&sm_h1[(32 * h + l31) * H_LD + kt * 16 + l5 * 8]);
        acc = __builtin_amdgcn_mfma_f32_32x32x16_f16(B2[kt], bf, acc, 0, 0, 0);
      }
      float p = 0.f;
#pragma unroll
      for (int r = 0; r < 16; ++r) p += fmaxf(acc[r], 0.f) * w3r[r];
      p += __shfl_xor(p, 32);          // combine l5 halves
      if (l5 == 0) sm_part[wv * 64 + 32 * h + l31] = p;
    }

    eprev = tile * MTILE;
  }

  __syncthreads();
  if (eprev >= 0 && tid < MTILE) {
    float s = sm_part[tid] + sm_part[64 + tid] + sm_part[128 + tid] + sm_part[192 + tid];
    out[eprev + tid] = s + bias3;
  }
}

// Fallback (ws too small for y cache): unchanged round-6 structure.
__global__ __launch_bounds__(256, 2) void mlp_edge_direct(
    const float* __restrict__ x1, const float* __restrict__ x2,
    const int* __restrict__ eidx,
    const unsigned short* __restrict__ W1t, const unsigned short* __restrict__ W2t,
    const float* __restrict__ b1, const float* __restrict__ b2,
    const float* __restrict__ W3, const float* __restrict__ b3,
    float* __restrict__ out, int E, int ntiles)
{
  __shared__ unsigned short sm_pair[MTILE * PAIR_LD];
  __shared__ unsigned short sm_h1[MTILE * H_LD];
  __shared__ float sm_w3[4 * 36];
  unsigned short* sm_h2 = sm_pair;

  const int tid = threadIdx.x;
  const int lane = tid & 63;
  const int wv = tid >> 6;
  const int l31 = lane & 31;
  const int l5 = lane >> 5;
  const int nb = wv * 32 + l31;

  v8bf B1[16], B2[8];
#pragma unroll
  for (int kt = 0; kt < 16; ++kt)
    B1[kt] = *reinterpret_cast<const v8bf*>(W1t + nb * 256 + kt * 16 + l5 * 8);
#pragma unroll
  for (int kt = 0; kt < 8; ++kt)
    B2[kt] = *reinterpret_cast<const v8bf*>(W2t + nb * 128 + kt * 16 + l5 * 8);
  const float b1v = b1[nb];
  const float b2v = b2[nb];
  const float bias3 = b3[0];
  if (tid < 128) sm_w3[(tid >> 5) * 36 + (tid & 31)] = W3[tid];

  const int rslot = tid >> 4;
  const int lane16 = tid & 15;
  const int part = tid & 3;

  for (int tile = blockIdx.x; tile < ntiles; tile += gridDim.x) {
    __syncthreads();
    const int e0 = tile * MTILE;
#pragma unroll
    for (int p = 0; p < 8; ++p) {
      int rowid = p * 16 + rslot;
      int half = rowid >> 6;
      int el = rowid & 63;
      int node = eidx[e0 + el + (half ? E : 0)];
      const float* src = (half ? x2 : x1) + (size_t)node * DIM + lane16 * 8;
      float4 f0 = *reinterpret_cast<const float4*>(src);
      float4 f1 = *reinterpret_cast<const float4*>(src + 4);
      uint4 pk;
      pk.x = f2bf_pack(f0.x, f0.y);
      pk.y = f2bf_pack(f0.z, f0.w);
      pk.z = f2bf_pack(f1.x, f1.y);
      pk.w = f2bf_pack(f1.z, f1.w);
      *reinterpret_cast<uint4*>(&sm_pair[el * PAIR_LD + half * 128 + lane16 * 8]) = pk;
    }
    __syncthreads();

    v16f acc0, acc1;
#pragma unroll
    for (int r = 0; r < 16; ++r) { acc0[r] = 0.f; acc1[r] = 0.f; }
#pragma unroll
    for (int kt = 0; kt < 16; ++kt) {
      v8bf a0 = *reinterpret_cast<const v8bf*>(&sm_pair[l31 * PAIR_LD + kt * 16 + l5 * 8]);
      v8bf a1 = *reinterpret_cast<const v8bf*>(&sm_pair[(32 + l31) * PAIR_LD + kt * 16 + l5 * 8]);
      acc0 = __builtin_amdgcn_mfma_f32_32x32x16_bf16(a0, B1[kt], acc0, 0, 0, 0);
      acc1 = __builtin_amdgcn_mfma_f32_32x32x16_bf16(a1, B1[kt], acc1, 0, 0, 0);
    }
#pragma unroll
    for (int r = 0; r < 16; ++r) {
      int m = (r & 3) + 8 * (r >> 2) + 4 * l5;
      sm_h1[m * H_LD + nb] = f2bf(fmaxf(acc0[r] + b1v, 0.f));
      sm_h1[(32 + m) * H_LD + nb] = f2bf(fmaxf(acc1[r] + b1v, 0.f));
    }
    __syncthreads();

    v16f c0, c1;
#pragma unroll
    for (int r = 0; r < 16; ++r) { c0[r] = 0.f; c1[r] = 0.f; }
#pragma unroll
    for (int kt = 0; kt < 8; ++kt) {
      v8bf a0 = *reinterpret_cast<const v8bf*>(&sm_h1[l31 * H_LD + kt * 16 + l5 * 8]);
      v8bf a1 = *reinterpret_cast<const v8bf*>(&sm_h1[(32 + l31) * H_LD + kt * 16 + l5 * 8]);
      c0 = __builtin_amdgcn_mfma_f32_32x32x16_bf16(a0, B2[kt], c0, 0, 0, 0);
      c1 = __builtin_amdgcn_mfma_f32_32x32x16_bf16(a1, B2[kt], c1, 0, 0, 0);
    }
#pragma unroll
    for (int r = 0; r < 16; ++r) {
      int m = (r & 3) + 8 * (r >> 2) + 4 * l5;
      sm_h2[m * H_LD + nb] = f2bf(fmaxf(c0[r] + b2v, 0.f));
      sm_h2[(32 + m) * H_LD + nb] = f2bf(fmaxf(c1[r] + b2v, 0.f));
    }
    __syncthreads();

    {
      int el = tid >> 2;
      const unsigned short* hrow = &sm_h2[el * H_LD + part * 32];
      const float* wrow = &sm_w3[part * 36];
      float sum = 0.f;
#pragma unroll
      for (int j = 0; j < 4; ++j) {
        uint4 u = *reinterpret_cast<const uint4*>(hrow + j * 8);
        float4 wa = *reinterpret_cast<const float4*>(wrow + j * 8);
        float4 wb = *reinterpret_cast<const float4*>(wrow + j * 8 + 4);
        sum += bfhi2f(u.x << 16) * wa.x + bfhi2f(u.x & 0xFFFF0000u) * wa.y;
        sum += bfhi2f(u.y << 16) * wa.z + bfhi2f(u.y & 0xFFFF0000u) * wa.w;
        sum += bfhi2f(u.z << 16) * wb.x + bfhi2f(u.z & 0xFFFF0000u) * wb.y;
        sum += bfhi2f(u.w << 16) * wb.z + bfhi2f(u.w & 0xFFFF0000u) * wb.w;
      }
      sum += __shfl_xor(sum, 1, 64);
      sum += __shfl_xor(sum, 2, 64);
      if (part == 0) out[e0 + el] = sum + bias3;
    }
  }
}

extern "C" void kernel_launch(void* const* d_in, const int* in_sizes, int n_in,
                              void* d_out, int out_size, void* d_ws, size_t ws_size,
                              hipStream_t stream) {
  const float* x1 = (const float*)d_in[0];
  const float* x2 = (const float*)d_in[1];
  const int* eidx = (const int*)d_in[2];
  const float* W1 = (const float*)d_in[3];
  const float* b1 = (const float*)d_in[4];
  const float* W2 = (const float*)d_in[5];
  const float* b2 = (const float*)d_in[6];
  const float* W3 = (const float*)d_in[7];
  const float* b3 = (const float*)d_in[8];
  float* out = (float*)d_out;

  int E = in_sizes[2] / 2;
  if (E <= 0) return;
  int ntiles = E / MTILE;           // E = 1,600,000 divisible by 64
  int nelem = in_sizes[0];          // nodes * DIM
  int nnodes = nelem / DIM;

  unsigned short* W1t = (unsigned short*)d_ws;         // 32768 bf16
  unsigned short* W2t = W1t + 32768;                   // 16384 bf16/fp16
  size_t woff = 98304;                                 // bytes used by weights
  size_t need = woff + 2 * (size_t)nelem * 2;          // y1c + y2c fp16
  int use_cache = (ws_size >= need) ? 1 : 0;
  unsigned short* y1c = (unsigned short*)((char*)d_ws + woff);
  unsigned short* y2c = y1c + nelem;

  prep_w<<<192, 256, 0, stream>>>(W1, W2, W1t, W2t, use_cache);

  if (use_cache) {
    int ntn = (nnodes + MTILE - 1) / MTILE;
    node_precompute<<<2 * ntn, 256, 0, stream>>>(x1, x2, W1t, b1, y1c, y2c, nnodes);
    // grid 2048: 8 blocks/CU resident (usage-limited: 60 VGPR, 18.4KB LDS)
    mlp_edge_y<<<2048, 256, 0, stream>>>(eidx, W2t, b2, W3, b3,
                                         out, E, ntiles, y1c, y2c);
  } else {
    mlp_edge_direct<<<512, 256, 0, stream>>>(x1, x2, eidx, W1t, W2t,
                                             b1, b2, W3, b3, out, E, ntiles);
  }
}